// Round 8
// baseline (804.641 us; speedup 1.0000x reference)
//
#include <hip/hip_runtime.h>
#include <hip/hip_bf16.h>

#define T_STEPS 512
#define BATCH   2048
#define ISZ     128
#define HSZ     64
#define VSZ     128
#define ZSZ     192   // I + H

#define MBLK    8     // batch rows per recurrence block -> 256 blocks
#define ATHREADS 256  // 4 identical waves
#define HLD     72    // hbuf row stride (bf16): 144 B
#define XROWB   512   // bytes per staged x row (128 f32)

typedef __attribute__((ext_vector_type(8))) short bf16x8;
typedef __attribute__((ext_vector_type(4))) float f32x4;

__device__ __forceinline__ unsigned short f2bf(float x) {
  union { float f; unsigned int u; } v; v.f = x;
  unsigned int u = v.u;
  unsigned int r = (u + 0x7fffu + ((u >> 16) & 1u)) >> 16;  // RNE
  return (unsigned short)r;
}

__device__ __forceinline__ unsigned short f2bf_hw(float x) {
  __hip_bfloat16 b = __float2bfloat16(x);
  return *reinterpret_cast<unsigned short*>(&b);
}

// branch-free, NaN-safe at +/-inf
__device__ __forceinline__ float fsig(float x) {
  float e = __expf(-x);
  return __builtin_amdgcn_rcpf(1.0f + e);
}
__device__ __forceinline__ float ftanh2(float x) {
  float e = __expf(-2.0f * x);
  return __builtin_amdgcn_rcpf(1.0f + e) * 2.0f - 1.0f;
}

__device__ __forceinline__ void stage16(const void* g, void* l) {
  __builtin_amdgcn_global_load_lds(
      (const __attribute__((address_space(1))) void*)g,
      (__attribute__((address_space(3))) void*)l, 16, 0, 0);
}

// ======== Kernel A: recurrence, 4 identical waves, lockstep s_barrier ========
__global__ __launch_bounds__(ATHREADS, 1) void lstm_rec(
    const float* __restrict__ x,
    const float* __restrict__ h0,
    const float* __restrict__ c0,
    const float* __restrict__ Wf,  const float* __restrict__ bf_,
    const float* __restrict__ Wif, const float* __restrict__ bif_,
    const float* __restrict__ Wic, const float* __restrict__ bic_,
    const float* __restrict__ Wo,  const float* __restrict__ bo_,
    float* __restrict__ out)
{
  // x ring: 4 slots x 4 waves x (8 rows x 512B), swizzled content, private per wave
  __shared__ __attribute__((aligned(16))) float xlds[4 * 4 * 1024];
  __shared__ unsigned short hbuf[2][16][HLD]; // h state (bf16), 2-ring

  const int tid  = threadIdx.x;
  const int wv   = tid >> 6;
  const int ln   = tid & 63;
  const int lrow = ln & 15;
  const int lkg  = ln >> 4;
  const int b0   = blockIdx.x * MBLK;
  const int hcol = 16 * wv + lrow;
  const int xrow = lrow & 7;          // A-frag row in the staged x tile
  const int xswz = xrow << 4;         // XOR swizzle for bank spread

  const float* Wg_[4] = {Wf, Wif, Wic, Wo};
  const float* bg_[4] = {bf_, bif_, bic_, bo_};

  // ---- weight fragments in registers ----
  bf16x8 fragWx[4][4];   // x-part  [gate][kf], K=128
  bf16x8 fragWh[4][2];   // h-part  [gate][kf], K=64
#pragma unroll
  for (int g = 0; g < 4; ++g) {
#pragma unroll
    for (int kf = 0; kf < 4; ++kf) {
      const float* p = Wg_[g] + hcol * ZSZ + kf * 32 + 8 * lkg;
      bf16x8 f;
#pragma unroll
      for (int e = 0; e < 8; ++e) f[e] = (short)f2bf(p[e]);
      fragWx[g][kf] = f;
    }
#pragma unroll
    for (int kf = 0; kf < 2; ++kf) {
      const float* p = Wg_[g] + hcol * ZSZ + ISZ + kf * 32 + 8 * lkg;
      bf16x8 f;
#pragma unroll
      for (int e = 0; e < 8; ++e) f[e] = (short)f2bf(p[e]);
      fragWh[g][kf] = f;
    }
  }
  float biasG[4];
#pragma unroll
  for (int g = 0; g < 4; ++g) biasG[g] = bg_[g][hcol];

  // cell state in C-layout: rows 4*lkg+e, col hcol; valid lanes lkg<2
  float cst[4] = {0.f, 0.f, 0.f, 0.f}, hh[4] = {0.f, 0.f, 0.f, 0.f};
  if (lkg < 2) {
#pragma unroll
    for (int e = 0; e < 4; ++e)
      cst[e] = c0[(b0 + 4 * lkg + e) * HSZ + hcol];
  }

  // ---- hbuf init: zero (rows 8..15 stay zero), stage h0 rows 0..7 ----
  for (int i = tid; i < 2 * 16 * HLD; i += ATHREADS)
    ((unsigned short*)hbuf)[i] = 0;
  __syncthreads();
  {
    int idx = tid * 2, r = idx >> 6, c = idx & 63;
    hbuf[0][r][c]     = f2bf(h0[(b0 + r) * HSZ + c]);
    hbuf[0][r][c + 1] = f2bf(h0[(b0 + r) * HSZ + c + 1]);
  }

  unsigned short* hout16 = (unsigned short*)out;  // bf16 h stash (head of probs rows)
  const size_t probs_elems = (size_t)T_STEPS * BATCH * VSZ;

// stage x[TT] into ring slot (TT)&3, this wave's private copy (4 DMA instrs)
#define STAGE(TT)                                                              \
  {                                                                            \
    const int tc = ((TT) < T_STEPS) ? (TT) : T_STEPS - 1;                      \
    const float* xb = x + (size_t)tc * BATCH * ISZ + (size_t)b0 * ISZ;         \
    char* lb = (char*)&xlds[(((TT) & 3) * 4 + wv) * 1024];                     \
    _Pragma("unroll")                                                          \
    for (int i = 0; i < 4; ++i) {                                              \
      const int row = 2 * i + (ln >> 5);                                       \
      const int scolb = ((ln & 31) * 16) ^ ((row & 7) << 4);                   \
      stage16((const char*)(xb + row * ISZ) + scolb, lb + i * 1024);           \
    }                                                                          \
  }

// read x[.] from ring slot RING (own copy), cvt, 16 MFMAs -> GOUT = gx
#define XBLOCK(RING, GOUT)                                                     \
  {                                                                            \
    asm volatile("s_waitcnt vmcnt(8)" ::: "memory");                           \
    const char* xrb =                                                          \
        (const char*)&xlds[((RING) * 4 + wv) * 1024] + xrow * XROWB;           \
    _Pragma("unroll")                                                          \
    for (int g = 0; g < 4; ++g)                                                \
      GOUT[g] = (f32x4){biasG[g], biasG[g], biasG[g], biasG[g]};               \
    _Pragma("unroll")                                                          \
    for (int kf = 0; kf < 4; ++kf) {                                           \
      const int cb = kf * 128 + lkg * 32;                                      \
      f32x4 a = *(const f32x4*)(xrb + ((cb) ^ xswz));                          \
      f32x4 b = *(const f32x4*)(xrb + ((cb + 16) ^ xswz));                     \
      bf16x8 f;                                                                \
      _Pragma("unroll")                                                        \
      for (int j = 0; j < 4; ++j) {                                            \
        f[j]     = (short)f2bf_hw(a[j]);                                       \
        f[4 + j] = (short)f2bf_hw(b[j]);                                       \
      }                                                                        \
      _Pragma("unroll")                                                        \
      for (int g = 0; g < 4; ++g)                                              \
        GOUT[g] = __builtin_amdgcn_mfma_f32_16x16x32_bf16(f, fragWx[g][kf],    \
                                                          GOUT[g], 0, 0, 0);   \
    }                                                                          \
  }

// one recurrence round: consume GIN = gx[T], produce GOUT = gx[T+1]
#define STEP(T, GIN, GOUT)                                                     \
  {                                                                            \
    const unsigned short* hrow = &hbuf[(T) & 1][lrow][0];                      \
    const bf16x8 hf0 = *(const bf16x8*)&hrow[8 * lkg];                         \
    const bf16x8 hf1 = *(const bf16x8*)&hrow[32 + 8 * lkg];                    \
    XBLOCK((((T) + 1) & 3), GOUT)                                              \
    f32x4 cur[4];                                                              \
    _Pragma("unroll")                                                          \
    for (int g = 0; g < 4; ++g)                                                \
      cur[g] = __builtin_amdgcn_mfma_f32_16x16x32_bf16(hf0, fragWh[g][0],      \
                                                       GIN[g], 0, 0, 0);       \
    _Pragma("unroll")                                                          \
    for (int g = 0; g < 4; ++g)                                                \
      cur[g] = __builtin_amdgcn_mfma_f32_16x16x32_bf16(hf1, fragWh[g][1],      \
                                                       cur[g], 0, 0, 0);       \
    if (lkg < 2) {                                                             \
      _Pragma("unroll")                                                        \
      for (int e = 0; e < 4; ++e) {                                            \
        const float fg = fsig(cur[0][e]);                                      \
        const float ig = fsig(cur[1][e]);                                      \
        const float cd = ftanh2(cur[2][e]);                                    \
        const float og = fsig(cur[3][e]);                                      \
        const float c  = cst[e] * fg + cd * ig;                                \
        cst[e] = c;                                                            \
        hh[e] = ftanh2(c) * og;                                                \
        const unsigned short hb = f2bf_hw(hh[e]);                              \
        hbuf[((T) + 1) & 1][4 * lkg + e][hcol] = hb;                           \
        hout16[((size_t)(T) * BATCH + b0 + 4 * lkg + e) * (2 * VSZ) + hcol] = hb; \
      }                                                                        \
    }                                                                          \
    STAGE((T) + 3)                                                             \
    asm volatile("s_waitcnt lgkmcnt(0)\n\ts_barrier" ::: "memory");            \
  }

  // ---- prologue: stage x0..x2, compute gx[0] ----
  f32x4 gxA[4], gxB[4];
  STAGE(0)
  STAGE(1)
  STAGE(2)
  XBLOCK(0, gxA)                                  // vmcnt(8) inside -> x0 ready
  asm volatile("s_waitcnt vmcnt(4)" ::: "memory"); // x1 retired too
  __syncthreads();   // h0 staged; all waves ready

  for (int t = 0; t < T_STEPS; t += 2) {
    STEP(t, gxA, gxB)
    STEP(t + 1, gxB, gxA)
  }

  // ---- final h/c outputs ----
  if (lkg < 2) {
#pragma unroll
    for (int e = 0; e < 4; ++e) {
      const int r = 4 * lkg + e;
      out[probs_elems + (size_t)(b0 + r) * HSZ + hcol] = hh[e];
      out[probs_elems + (size_t)BATCH * HSZ + (size_t)(b0 + r) * HSZ + hcol] = cst[e];
    }
  }
#undef STEP
#undef XBLOCK
#undef STAGE
}

// ========== Kernel B: out-proj + softmax, fully parallel over T x B ==========
#define BBLOCKS 2048
__global__ __launch_bounds__(256) void lstm_out(
    const float* __restrict__ Wout, const float* __restrict__ bout_,
    float* __restrict__ out)
{
  const int tid  = threadIdx.x;
  const int wv   = tid >> 6;
  const int ln   = tid & 63;
  const int lrow = ln & 15;
  const int lkg  = ln >> 4;

  bf16x8 fragWo[8][2];
#pragma unroll
  for (int rf = 0; rf < 8; ++rf)
#pragma unroll
    for (int kf = 0; kf < 2; ++kf) {
      const float* p = Wout + (16 * rf + lrow) * HSZ + kf * 32 + 8 * lkg;
      bf16x8 f;
#pragma unroll
      for (int e = 0; e < 8; ++e) f[e] = (short)f2bf(p[e]);
      fragWo[rf][kf] = f;
    }
  f32x4 boV[8];
#pragma unroll
  for (int rf = 0; rf < 8; ++rf) boV[rf] = *(const f32x4*)&bout_[16 * rf + 4 * lkg];

  const unsigned short* hin = (const unsigned short*)out;
  const int NT = T_STEPS * (BATCH / 16);
  const int nw = BBLOCKS * 4;

  for (int tile = blockIdx.x * 4 + wv; tile < NT; tile += nw) {
    const int t  = tile >> 7;
    const int b0 = (tile & 127) * 16;

    const unsigned short* hr = hin + ((size_t)t * BATCH + b0 + lrow) * (2 * VSZ);
    const bf16x8 hb0 = *(const bf16x8*)&hr[8 * lkg];
    const bf16x8 hb1 = *(const bf16x8*)&hr[32 + 8 * lkg];

    f32x4 lac[8];
#pragma unroll
    for (int rf = 0; rf < 8; ++rf) {
      lac[rf] = boV[rf];
      lac[rf] = __builtin_amdgcn_mfma_f32_16x16x32_bf16(fragWo[rf][0], hb0, lac[rf], 0, 0, 0);
      lac[rf] = __builtin_amdgcn_mfma_f32_16x16x32_bf16(fragWo[rf][1], hb1, lac[rf], 0, 0, 0);
    }

    float m = -1e30f;
#pragma unroll
    for (int rf = 0; rf < 8; ++rf)
#pragma unroll
      for (int e = 0; e < 4; ++e) m = fmaxf(m, lac[rf][e]);
    m = fmaxf(m, __shfl_xor(m, 16));
    m = fmaxf(m, __shfl_xor(m, 32));
    float s = 0.0f;
#pragma unroll
    for (int rf = 0; rf < 8; ++rf)
#pragma unroll
      for (int e = 0; e < 4; ++e) {
        float p = __expf(lac[rf][e] - m);
        lac[rf][e] = p;
        s += p;
      }
    s += __shfl_xor(s, 16);
    s += __shfl_xor(s, 32);
    const float inv = 1.0f / s;

    float* orow = &out[((size_t)t * BATCH + b0 + lrow) * VSZ];
#pragma unroll
    for (int rf = 0; rf < 8; ++rf) {
      f32x4 pv = lac[rf] * inv;
      *(f32x4*)&orow[16 * rf + 4 * lkg] = pv;
    }
  }
}

extern "C" void kernel_launch(void* const* d_in, const int* in_sizes, int n_in,
                              void* d_out, int out_size, void* d_ws, size_t ws_size,
                              hipStream_t stream) {
  const float* x    = (const float*)d_in[0];
  const float* h0   = (const float*)d_in[1];
  const float* c0   = (const float*)d_in[2];
  const float* Wf   = (const float*)d_in[3];
  const float* bf_  = (const float*)d_in[4];
  const float* Wif  = (const float*)d_in[5];
  const float* bif_ = (const float*)d_in[6];
  const float* Wic  = (const float*)d_in[7];
  const float* bic_ = (const float*)d_in[8];
  const float* Wo   = (const float*)d_in[9];
  const float* bo_  = (const float*)d_in[10];
  const float* Wout = (const float*)d_in[11];
  const float* bout = (const float*)d_in[12];
  float* out = (float*)d_out;

  hipLaunchKernelGGL(lstm_rec, dim3(BATCH / MBLK), dim3(ATHREADS), 0, stream,
                     x, h0, c0, Wf, bf_, Wif, bif_, Wic, bic_, Wo, bo_, out);
  hipLaunchKernelGGL(lstm_out, dim3(BBLOCKS), dim3(256), 0, stream,
                     Wout, bout, out);
}

// Round 9
// 648.937 us; speedup vs baseline: 1.2399x; 1.2399x over previous
//
#include <hip/hip_runtime.h>
#include <hip/hip_bf16.h>

#define T_STEPS 512
#define BATCH   2048
#define ISZ     128
#define HSZ     64
#define VSZ     128
#define ZSZ     192   // I + H

#define MBLK    8     // batch rows per recurrence block -> 256 blocks
#define ATHREADS 512  // 4 P-waves + 4 X-waves

typedef __attribute__((ext_vector_type(8))) short bf16x8;
typedef __attribute__((ext_vector_type(4))) float f32x4;
typedef __attribute__((ext_vector_type(4))) unsigned short u16x4;

__device__ __forceinline__ unsigned short f2bf(float x) {
  union { float f; unsigned int u; } v; v.f = x;
  unsigned int u = v.u;
  unsigned int r = (u + 0x7fffu + ((u >> 16) & 1u)) >> 16;  // RNE
  return (unsigned short)r;
}

__device__ __forceinline__ unsigned short f2bf_hw(float x) {
  __hip_bfloat16 b = __float2bfloat16(x);
  return *reinterpret_cast<unsigned short*>(&b);
}

// branch-free, NaN-safe at +/-inf (validated round 8: absmax 0.0078)
__device__ __forceinline__ float fsig(float x) {
  float e = __expf(-x);
  return __builtin_amdgcn_rcpf(1.0f + e);
}
__device__ __forceinline__ float ftanh2(float x) {
  float e = __expf(-2.0f * x);
  return __builtin_amdgcn_rcpf(1.0f + e) * 2.0f - 1.0f;
}

// ======== Kernel A: lockstep rounds — P (h-chain, transposed C) + X (x-GEMM) ==
__global__ __launch_bounds__(ATHREADS, 1) void lstm_rec(
    const float* __restrict__ x,
    const float* __restrict__ h0,
    const float* __restrict__ c0,
    const float* __restrict__ Wf,  const float* __restrict__ bf_,
    const float* __restrict__ Wif, const float* __restrict__ bif_,
    const float* __restrict__ Wic, const float* __restrict__ bic_,
    const float* __restrict__ Wo,  const float* __restrict__ bo_,
    float* __restrict__ out)
{
  // gbuf: [slot 3][xw 4][(g*4+lkg) 16][lrow 16][4] f32 — raw C-fragments, bias added
  __shared__ __attribute__((aligned(16))) float gbuf[3 * 4 * 16 * 64];
  // hbuf: [slot 2][batch row 16][hcol 64] bf16, XOR-swizzled ((row&7)<<4 on bytes)
  __shared__ __attribute__((aligned(16))) unsigned short hbuf[2 * 16 * 64];

  const int tid  = threadIdx.x;
  const int wv   = tid >> 6;     // 0..3 = P, 4..7 = X
  const int ln   = tid & 63;
  const int lrow = ln & 15;
  const int lkg  = ln >> 4;
  const int b0   = blockIdx.x * MBLK;
  const int swz  = (lrow & 7) << 4;

  // zero hbuf (rows 8..15 stay zero forever)
  for (int i = tid; i < 2 * 16 * 64; i += ATHREADS) hbuf[i] = 0;
  __syncthreads();
  if (tid < 128) {   // stage h0 rows 0..7, swizzled, packed b64
    const int r = tid >> 4, cb = tid & 15;
    f32x4 hv = *(const f32x4*)&h0[(b0 + r) * HSZ + cb * 4];
    u16x4 pk;
#pragma unroll
    for (int j = 0; j < 4; ++j) pk[j] = f2bf(hv[j]);
    *(u16x4*)((char*)hbuf + r * 128 + ((cb * 8) ^ ((r & 7) << 4))) = pk;
  }

  const float* Wg_[4] = {Wf, Wif, Wic, Wo};
  const float* bg_[4] = {bf_, bif_, bic_, bo_};
  const size_t probs_elems = (size_t)T_STEPS * BATCH * VSZ;

  if (wv < 4) {
    // ========== P-wave: minimal h-chain, transposed-C cell update ==========
    const int hcol = 16 * wv + lrow;   // fragWh A-row

    bf16x8 fragWh[4][2];               // A-operand: W[g][16wv+lrow][128+kf*32+8lkg+j]
#pragma unroll
    for (int g = 0; g < 4; ++g)
#pragma unroll
      for (int kf = 0; kf < 2; ++kf) {
        const float* p = Wg_[g] + hcol * ZSZ + ISZ + kf * 32 + 8 * lkg;
        bf16x8 f;
#pragma unroll
        for (int e = 0; e < 8; ++e) f[e] = (short)f2bf(p[e]);
        fragWh[g][kf] = f;
      }

    // cell state: lane(lkg,lrow) owns batch row lrow, hcols 16wv+4lkg+0..3
    f32x4 cst = {0.f, 0.f, 0.f, 0.f}, hhv = {0.f, 0.f, 0.f, 0.f};
    if (lrow < MBLK)
      cst = *(const f32x4*)&c0[(b0 + lrow) * HSZ + 16 * wv + 4 * lkg];

    unsigned short* hout16 = (unsigned short*)out;
    __builtin_amdgcn_s_setprio(1);
    __syncthreads();   // (B): X produced g[0], g[1]

    // prologue preload: acc = g[0] (slot 0)
    f32x4 acc[4];
    {
      const float* gs = &gbuf[(0 * 4 + wv) * 1024];
#pragma unroll
      for (int g = 0; g < 4; ++g)
        acc[g] = *(const f32x4*)&gs[(g * 4 + lkg) * 64 + lrow * 4];
    }

    int sN = 1;   // slot of g[t+1] to preload during round t
    for (int t = 0; t < T_STEPS; ++t) {
      __builtin_amdgcn_s_barrier();
      asm volatile("" ::: "memory");

      // h[t] B-fragments (z^T): lane reads h[hcol 8lkg..+8 / +32..][batch lrow]
      const char* hbase = (const char*)hbuf + (t & 1) * 2048 + lrow * 128;
      const bf16x8 hB0 = *(const bf16x8*)(hbase + ((lkg * 16) ^ swz));
      const bf16x8 hB1 = *(const bf16x8*)(hbase + ((64 + lkg * 16) ^ swz));

      f32x4 cur[4];
#pragma unroll
      for (int g = 0; g < 4; ++g)
        cur[g] = __builtin_amdgcn_mfma_f32_16x16x32_bf16(fragWh[g][0], hB0, acc[g], 0, 0, 0);
#pragma unroll
      for (int g = 0; g < 4; ++g)
        cur[g] = __builtin_amdgcn_mfma_f32_16x16x32_bf16(fragWh[g][1], hB1, cur[g], 0, 0, 0);

      // preload next round's x-part acc (off-chain; X wrote it >=1 barrier ago)
      {
        const float* gs = &gbuf[(sN * 4 + wv) * 1024];
#pragma unroll
        for (int g = 0; g < 4; ++g)
          acc[g] = *(const f32x4*)&gs[(g * 4 + lkg) * 64 + lrow * 4];
        sN = (sN == 2) ? 0 : sN + 1;
      }

      // cell update: all in-lane (C rows = gatecols, C col = batch row lrow)
      if (lrow < MBLK) {
        u16x4 pk;
#pragma unroll
        for (int e = 0; e < 4; ++e) {
          const float fg = fsig(cur[0][e]);
          const float ig = fsig(cur[1][e]);
          const float cd = ftanh2(cur[2][e]);
          const float og = fsig(cur[3][e]);
          const float c  = cst[e] * fg + cd * ig;
          cst[e] = c;
          hhv[e] = ftanh2(c) * og;
          pk[e] = f2bf_hw(hhv[e]);
        }
        // publish h[t+1]: one b64 LDS write (swizzled) + one b64 global stash
        *(u16x4*)((char*)hbuf + ((t + 1) & 1) * 2048 + lrow * 128 +
                  ((32 * wv + 8 * lkg) ^ swz)) = pk;
        *(u16x4*)&hout16[((size_t)t * BATCH + b0 + lrow) * (2 * VSZ) +
                         16 * wv + 4 * lkg] = pk;
      }

      asm volatile("s_waitcnt lgkmcnt(0)" ::: "memory");
    }

    // final h/c outputs
    if (lrow < MBLK) {
      *(f32x4*)&out[probs_elems + (size_t)(b0 + lrow) * HSZ + 16 * wv + 4 * lkg] = hhv;
      *(f32x4*)&out[probs_elems + (size_t)BATCH * HSZ +
                    (size_t)(b0 + lrow) * HSZ + 16 * wv + 4 * lkg] = cst;
    }
  } else {
    // ========== X-wave: x[t]-GEMM producer (transposed), 2 rounds ahead ======
    const int xw = wv - 4;
    const int hcolX = 16 * xw + lrow;

    bf16x8 fragWx[4][4];               // A-operand: W[g][16xw+lrow][kf*32+8lkg+j]
#pragma unroll
    for (int g = 0; g < 4; ++g)
#pragma unroll
      for (int kf = 0; kf < 4; ++kf) {
        const float* p = Wg_[g] + hcolX * ZSZ + kf * 32 + 8 * lkg;
        bf16x8 f;
#pragma unroll
        for (int e = 0; e < 8; ++e) f[e] = (short)f2bf(p[e]);
        fragWx[g][kf] = f;
      }
    f32x4 biasV[4];                    // C rows 4lkg+e -> bias[g][16xw+4lkg+e]
#pragma unroll
    for (int g = 0; g < 4; ++g)
      biasV[g] = *(const f32x4*)&bg_[g][16 * xw + 4 * lkg];

    const int rowx = min(b0 + lrow, BATCH - 1);
    const int xoff = 8 * lkg;

    f32x4 rEa[4], rEb[4], rOa[4], rOb[4];

#define XLOAD(TT, RA, RB)                                                      \
    {                                                                          \
      const int tc = ((TT) < T_STEPS) ? (TT) : T_STEPS - 1;                    \
      const float* xp = x + (size_t)tc * BATCH * ISZ + (size_t)rowx * ISZ;     \
      _Pragma("unroll")                                                        \
      for (int kf = 0; kf < 4; ++kf) {                                         \
        RA[kf] = *(const f32x4*)&xp[kf * 32 + xoff];                           \
        RB[kf] = *(const f32x4*)&xp[kf * 32 + xoff + 4];                       \
      }                                                                        \
    }

#define XPRODUCE(U, SLOT, RA, RB)                                              \
    if ((U) < T_STEPS) {                                                       \
      bf16x8 xf[4];                                                            \
      _Pragma("unroll")                                                        \
      for (int kf = 0; kf < 4; ++kf) {                                         \
        bf16x8 f;                                                              \
        _Pragma("unroll")                                                      \
        for (int j = 0; j < 4; ++j) {                                          \
          f[j]     = (short)f2bf_hw(RA[kf][j]);                                \
          f[4 + j] = (short)f2bf_hw(RB[kf][j]);                                \
        }                                                                      \
        xf[kf] = f;                                                            \
      }                                                                        \
      f32x4 xacc[4];                                                           \
      _Pragma("unroll")                                                        \
      for (int g = 0; g < 4; ++g) xacc[g] = biasV[g];                          \
      _Pragma("unroll")                                                        \
      for (int kf = 0; kf < 4; ++kf)                                           \
        _Pragma("unroll")                                                      \
        for (int g = 0; g < 4; ++g)                                            \
          xacc[g] = __builtin_amdgcn_mfma_f32_16x16x32_bf16(                   \
              fragWx[g][kf], xf[kf], xacc[g], 0, 0, 0);                        \
      float* gsw = &gbuf[((SLOT) * 4 + xw) * 1024];                            \
      _Pragma("unroll")                                                        \
      for (int g = 0; g < 4; ++g)                                              \
        *(f32x4*)&gsw[(g * 4 + lkg) * 64 + lrow * 4] = xacc[g];                \
    }

    // prologue: produce g[0], g[1]; leave x[2], x[3] in flight
    XLOAD(0, rEa, rEb);
    XLOAD(1, rOa, rOb);
    XPRODUCE(0, 0, rEa, rEb);
    XPRODUCE(1, 1, rOa, rOb);
    XLOAD(2, rEa, rEb);
    XLOAD(3, rOa, rOb);
    asm volatile("s_waitcnt lgkmcnt(0)" ::: "memory");
    __syncthreads();   // (B)

    int se = 2;  // slot for g[t+2] at even t
    int so = 0;  // slot for g[t+3]
    for (int t = 0; t < T_STEPS; t += 2) {
      __builtin_amdgcn_s_barrier();
      asm volatile("" ::: "memory");
      XPRODUCE(t + 2, se, rEa, rEb)
      XLOAD(t + 4, rEa, rEb);
      se += 2; if (se >= 3) se -= 3;
      asm volatile("s_waitcnt lgkmcnt(0)" ::: "memory");

      __builtin_amdgcn_s_barrier();
      asm volatile("" ::: "memory");
      XPRODUCE(t + 3, so, rOa, rOb)
      XLOAD(t + 5, rOa, rOb);
      so += 2; if (so >= 3) so -= 3;
      asm volatile("s_waitcnt lgkmcnt(0)" ::: "memory");
    }
#undef XPRODUCE
#undef XLOAD
  }
}

// ========== Kernel B: out-proj + softmax, fully parallel over T x B ==========
#define BBLOCKS 2048
__global__ __launch_bounds__(256) void lstm_out(
    const float* __restrict__ Wout, const float* __restrict__ bout_,
    float* __restrict__ out)
{
  const int tid  = threadIdx.x;
  const int wv   = tid >> 6;
  const int ln   = tid & 63;
  const int lrow = ln & 15;
  const int lkg  = ln >> 4;

  bf16x8 fragWo[8][2];
#pragma unroll
  for (int rf = 0; rf < 8; ++rf)
#pragma unroll
    for (int kf = 0; kf < 2; ++kf) {
      const float* p = Wout + (16 * rf + lrow) * HSZ + kf * 32 + 8 * lkg;
      bf16x8 f;
#pragma unroll
      for (int e = 0; e < 8; ++e) f[e] = (short)f2bf(p[e]);
      fragWo[rf][kf] = f;
    }
  f32x4 boV[8];
#pragma unroll
  for (int rf = 0; rf < 8; ++rf) boV[rf] = *(const f32x4*)&bout_[16 * rf + 4 * lkg];

  const unsigned short* hin = (const unsigned short*)out;
  const int NT = T_STEPS * (BATCH / 16);
  const int nw = BBLOCKS * 4;

  for (int tile = blockIdx.x * 4 + wv; tile < NT; tile += nw) {
    const int t  = tile >> 7;
    const int b0 = (tile & 127) * 16;

    const unsigned short* hr = hin + ((size_t)t * BATCH + b0 + lrow) * (2 * VSZ);
    const bf16x8 hb0 = *(const bf16x8*)&hr[8 * lkg];
    const bf16x8 hb1 = *(const bf16x8*)&hr[32 + 8 * lkg];

    f32x4 lac[8];
#pragma unroll
    for (int rf = 0; rf < 8; ++rf) {
      lac[rf] = boV[rf];
      lac[rf] = __builtin_amdgcn_mfma_f32_16x16x32_bf16(fragWo[rf][0], hb0, lac[rf], 0, 0, 0);
      lac[rf] = __builtin_amdgcn_mfma_f32_16x16x32_bf16(fragWo[rf][1], hb1, lac[rf], 0, 0, 0);
    }

    float m = -1e30f;
#pragma unroll
    for (int rf = 0; rf < 8; ++rf)
#pragma unroll
      for (int e = 0; e < 4; ++e) m = fmaxf(m, lac[rf][e]);
    m = fmaxf(m, __shfl_xor(m, 16));
    m = fmaxf(m, __shfl_xor(m, 32));
    float s = 0.0f;
#pragma unroll
    for (int rf = 0; rf < 8; ++rf)
#pragma unroll
      for (int e = 0; e < 4; ++e) {
        float p = __expf(lac[rf][e] - m);
        lac[rf][e] = p;
        s += p;
      }
    s += __shfl_xor(s, 16);
    s += __shfl_xor(s, 32);
    const float inv = 1.0f / s;

    float* orow = &out[((size_t)t * BATCH + b0 + lrow) * VSZ];
#pragma unroll
    for (int rf = 0; rf < 8; ++rf) {
      f32x4 pv = lac[rf] * inv;
      *(f32x4*)&orow[16 * rf + 4 * lkg] = pv;
    }
  }
}

extern "C" void kernel_launch(void* const* d_in, const int* in_sizes, int n_in,
                              void* d_out, int out_size, void* d_ws, size_t ws_size,
                              hipStream_t stream) {
  const float* x    = (const float*)d_in[0];
  const float* h0   = (const float*)d_in[1];
  const float* c0   = (const float*)d_in[2];
  const float* Wf   = (const float*)d_in[3];
  const float* bf_  = (const float*)d_in[4];
  const float* Wif  = (const float*)d_in[5];
  const float* bif_ = (const float*)d_in[6];
  const float* Wic  = (const float*)d_in[7];
  const float* bic_ = (const float*)d_in[8];
  const float* Wo   = (const float*)d_in[9];
  const float* bo_  = (const float*)d_in[10];
  const float* Wout = (const float*)d_in[11];
  const float* bout = (const float*)d_in[12];
  float* out = (float*)d_out;

  hipLaunchKernelGGL(lstm_rec, dim3(BATCH / MBLK), dim3(ATHREADS), 0, stream,
                     x, h0, c0, Wf, bf_, Wif, bif_, Wic, bic_, Wo, bo_, out);
  hipLaunchKernelGGL(lstm_out, dim3(BBLOCKS), dim3(256), 0, stream,
                     Wout, bout, out);
}

// Round 10
// 548.779 us; speedup vs baseline: 1.4662x; 1.1825x over previous
//
#include <hip/hip_runtime.h>
#include <hip/hip_bf16.h>

#define T_STEPS 512
#define BATCH   2048
#define ISZ     128
#define HSZ     64
#define VSZ     128
#define ZSZ     192   // I + H

#define MBLK    8     // batch rows per recurrence block -> 256 blocks
#define ATHREADS 512  // 4 P-waves + 4 X-waves

typedef __attribute__((ext_vector_type(8))) short bf16x8;
typedef __attribute__((ext_vector_type(4))) float f32x4;
typedef __attribute__((ext_vector_type(4))) unsigned short u16x4;

__device__ __forceinline__ unsigned short f2bf(float x) {
  union { float f; unsigned int u; } v; v.f = x;
  unsigned int u = v.u;
  unsigned int r = (u + 0x7fffu + ((u >> 16) & 1u)) >> 16;  // RNE
  return (unsigned short)r;
}

__device__ __forceinline__ unsigned short f2bf_hw(float x) {
  __hip_bfloat16 b = __float2bfloat16(x);
  return *reinterpret_cast<unsigned short*>(&b);
}

// branch-free, NaN-safe at +/-inf (validated rounds 8-9)
__device__ __forceinline__ float fsig(float x) {
  float e = __expf(-x);
  return __builtin_amdgcn_rcpf(1.0f + e);
}
__device__ __forceinline__ float ftanh2(float x) {
  float e = __expf(-2.0f * x);
  return __builtin_amdgcn_rcpf(1.0f + e) * 2.0f - 1.0f;
}

__device__ __forceinline__ void stage16(const void* g, void* l) {
  __builtin_amdgcn_global_load_lds(
      (const __attribute__((address_space(1))) void*)g,
      (__attribute__((address_space(3))) void*)l, 16, 0, 0);
}

// ======== Kernel A: lockstep rounds — P (h-chain) + X (DMA + time-packed x-GEMM)
__global__ __launch_bounds__(ATHREADS, 1) void lstm_rec(
    const float* __restrict__ x,
    const float* __restrict__ h0,
    const float* __restrict__ c0,
    const float* __restrict__ Wf,  const float* __restrict__ bf_,
    const float* __restrict__ Wif, const float* __restrict__ bif_,
    const float* __restrict__ Wic, const float* __restrict__ bic_,
    const float* __restrict__ Wo,  const float* __restrict__ bo_,
    float* __restrict__ out)
{
  // gbuf[slot4][xw4][(g*4+lkg)16][col8][4e] f32 — compressed C-fragments, bias added
  __shared__ __attribute__((aligned(16))) float gbuf[4][4][512];
  // xbuf: 5-slot ring of x tiles [8 rows][512B], swizzled content (DMA-staged)
  __shared__ __attribute__((aligned(16))) float xbuf[5][1024];
  // hbuf: [slot2][row16][col64] bf16, XOR-swizzled ((row&7)<<4 on bytes)
  __shared__ __attribute__((aligned(16))) unsigned short hbuf[2 * 16 * 64];

  const int tid  = threadIdx.x;
  const int wv   = tid >> 6;     // 0..3 = P, 4..7 = X
  const int ln   = tid & 63;
  const int lrow = ln & 15;
  const int lkg  = ln >> 4;
  const int b0   = blockIdx.x * MBLK;
  const int swz  = (lrow & 7) << 4;

  // zero hbuf (rows 8..15 stay zero forever)
  for (int i = tid; i < 2 * 16 * 64; i += ATHREADS) hbuf[i] = 0;
  __syncthreads();
  if (tid < 128) {   // stage h0 rows 0..7, swizzled, packed b64
    const int r = tid >> 4, cb = tid & 15;
    f32x4 hv = *(const f32x4*)&h0[(b0 + r) * HSZ + cb * 4];
    u16x4 pk;
#pragma unroll
    for (int j = 0; j < 4; ++j) pk[j] = f2bf(hv[j]);
    *(u16x4*)((char*)hbuf + r * 128 + ((cb * 8) ^ ((r & 7) << 4))) = pk;
  }

  const float* Wg_[4] = {Wf, Wif, Wic, Wo};
  const float* bg_[4] = {bf_, bif_, bic_, bo_};
  const size_t probs_elems = (size_t)T_STEPS * BATCH * VSZ;

  if (wv < 4) {
    // ========== P-wave: minimal h-chain, transposed-C cell update ==========
    const int hcol = 16 * wv + lrow;   // fragWh A-row

    bf16x8 fragWh[4][2];               // A: W[g][16wv+lrow][128 + kf*32 + 8lkg + j]
#pragma unroll
    for (int g = 0; g < 4; ++g)
#pragma unroll
      for (int kf = 0; kf < 2; ++kf) {
        const float* p = Wg_[g] + hcol * ZSZ + ISZ + kf * 32 + 8 * lkg;
        bf16x8 f;
#pragma unroll
        for (int e = 0; e < 8; ++e) f[e] = (short)f2bf(p[e]);
        fragWh[g][kf] = f;
      }

    // cell state: lane(lkg,lrow) owns batch row lrow (<8), hcols 16wv+4lkg+e
    f32x4 cst = {0.f, 0.f, 0.f, 0.f}, hhv = {0.f, 0.f, 0.f, 0.f};
    if (lrow < MBLK)
      cst = *(const f32x4*)&c0[(b0 + lrow) * HSZ + 16 * wv + 4 * lkg];

    unsigned short* hout16 = (unsigned short*)out;
    __builtin_amdgcn_s_setprio(1);
    __syncthreads();   // (B): X produced g[0], g[1]

    // preload acc = g[0] (slot 0)
    f32x4 acc[4];
    {
      const float* gs = &gbuf[0][wv][0];
#pragma unroll
      for (int g = 0; g < 4; ++g)
        acc[g] = *(const f32x4*)&gs[((g * 4 + lkg) * 8 + (lrow & 7)) * 4];
    }

    for (int t = 0; t < T_STEPS; ++t) {
      __builtin_amdgcn_s_barrier();
      asm volatile("" ::: "memory");

      // h[t] B-fragments (z^T)
      const char* hbase = (const char*)hbuf + (t & 1) * 2048 + lrow * 128;
      const bf16x8 hB0 = *(const bf16x8*)(hbase + ((lkg * 16) ^ swz));
      const bf16x8 hB1 = *(const bf16x8*)(hbase + ((64 + lkg * 16) ^ swz));

      f32x4 cur[4];
#pragma unroll
      for (int g = 0; g < 4; ++g)
        cur[g] = __builtin_amdgcn_mfma_f32_16x16x32_bf16(fragWh[g][0], hB0, acc[g], 0, 0, 0);
#pragma unroll
      for (int g = 0; g < 4; ++g)
        cur[g] = __builtin_amdgcn_mfma_f32_16x16x32_bf16(fragWh[g][1], hB1, cur[g], 0, 0, 0);

      // preload next round's x-part acc (written by X >=1 barrier ago)
      {
        const float* gs = &gbuf[(t + 1) & 3][wv][0];
#pragma unroll
        for (int g = 0; g < 4; ++g)
          acc[g] = *(const f32x4*)&gs[((g * 4 + lkg) * 8 + (lrow & 7)) * 4];
      }

      // cell update: fully in-lane
      if (lrow < MBLK) {
        u16x4 pk;
#pragma unroll
        for (int e = 0; e < 4; ++e) {
          const float fg = fsig(cur[0][e]);
          const float ig = fsig(cur[1][e]);
          const float cd = ftanh2(cur[2][e]);
          const float og = fsig(cur[3][e]);
          const float c  = cst[e] * fg + cd * ig;
          cst[e] = c;
          hhv[e] = ftanh2(c) * og;
          pk[e] = f2bf_hw(hhv[e]);
        }
        // publish h[t+1]: one swizzled b64 LDS write + one b64 global stash
        *(u16x4*)((char*)hbuf + ((t + 1) & 1) * 2048 + lrow * 128 +
                  ((32 * wv + 8 * lkg) ^ swz)) = pk;
        *(u16x4*)&hout16[((size_t)t * BATCH + b0 + lrow) * (2 * VSZ) +
                         16 * wv + 4 * lkg] = pk;
      }

      asm volatile("s_waitcnt lgkmcnt(0)" ::: "memory");
    }

    // final h/c outputs
    if (lrow < MBLK) {
      *(f32x4*)&out[probs_elems + (size_t)(b0 + lrow) * HSZ + 16 * wv + 4 * lkg] = hhv;
      *(f32x4*)&out[probs_elems + (size_t)BATCH * HSZ +
                    (size_t)(b0 + lrow) * HSZ + 16 * wv + 4 * lkg] = cst;
    }
  } else {
    // ========== X-wave: DMA x + time-packed x-GEMM (pairs), 2+ rounds ahead ==
    const int xw = wv - 4;
    const int hcolX = 16 * xw + lrow;

    bf16x8 fragWx[4][4];               // A: W[g][16xw+lrow][kf*32 + 8lkg + j]
#pragma unroll
    for (int g = 0; g < 4; ++g)
#pragma unroll
      for (int kf = 0; kf < 4; ++kf) {
        const float* p = Wg_[g] + hcolX * ZSZ + kf * 32 + 8 * lkg;
        bf16x8 f;
#pragma unroll
        for (int e = 0; e < 8; ++e) f[e] = (short)f2bf(p[e]);
        fragWx[g][kf] = f;
      }
    f32x4 biasV[4];                    // C rows 4lkg+e -> bias[g][16xw+4lkg+e]
#pragma unroll
    for (int g = 0; g < 4; ++g)
      biasV[g] = *(const f32x4*)&bg_[g][16 * xw + 4 * lkg];

// DMA one x tile (8 rows x 512B) into xbuf[SLOT], pre-swizzled source (rule #21)
#define STAGE(TT, SLOT)                                                        \
    {                                                                          \
      const int tc = ((TT) < T_STEPS) ? (TT) : T_STEPS - 1;                    \
      const char* xb = (const char*)(x + (size_t)tc * BATCH * ISZ +            \
                                     (size_t)b0 * ISZ);                        \
      char* lb = (char*)&xbuf[SLOT][0];                                        \
      _Pragma("unroll")                                                        \
      for (int i = 0; i < 4; ++i) {                                            \
        const int row = 2 * i + (ln >> 5);                                     \
        const int sc = ((ln & 31) * 16) ^ ((row & 7) << 4);                    \
        stage16(xb + row * 512 + sc, lb + i * 1024);                           \
      }                                                                        \
    }

// produce pair g[.] even-slot SE / odd-slot SO (tiles), gbuf slots GE / GO
#define XPAIR(SE, SO, GE, GO)                                                  \
    {                                                                          \
      const char* xt = (const char*)&xbuf[(lrow & 8) ? (SO) : (SE)][0] +       \
                       (lrow & 7) * 512;                                       \
      f32x4 xacc[4];                                                           \
      _Pragma("unroll")                                                        \
      for (int g = 0; g < 4; ++g) xacc[g] = biasV[g];                          \
      _Pragma("unroll")                                                        \
      for (int kf = 0; kf < 4; ++kf) {                                         \
        const int cb = kf * 128 + lkg * 32;                                    \
        f32x4 a = *(const f32x4*)(xt + ((cb) ^ swz));                          \
        f32x4 b = *(const f32x4*)(xt + ((cb + 16) ^ swz));                     \
        bf16x8 f;                                                              \
        _Pragma("unroll")                                                      \
        for (int j = 0; j < 4; ++j) {                                          \
          f[j]     = (short)f2bf_hw(a[j]);                                     \
          f[4 + j] = (short)f2bf_hw(b[j]);                                     \
        }                                                                      \
        _Pragma("unroll")                                                      \
        for (int g = 0; g < 4; ++g)                                            \
          xacc[g] = __builtin_amdgcn_mfma_f32_16x16x32_bf16(                   \
              fragWx[g][kf], f, xacc[g], 0, 0, 0);                             \
      }                                                                        \
      float* gdst = (lrow & 8) ? &gbuf[GO][xw][0] : &gbuf[GE][xw][0];          \
      _Pragma("unroll")                                                        \
      for (int g = 0; g < 4; ++g)                                              \
        *(f32x4*)&gdst[((g * 4 + lkg) * 8 + (lrow & 7)) * 4] = xacc[g];        \
    }

    // prologue: stage tiles 0..4; produce g[0],g[1] (cols packed by parity)
    STAGE(0, 0) STAGE(1, 1) STAGE(2, 2) STAGE(3, 3) STAGE(4, 4)
    asm volatile("s_waitcnt vmcnt(12)" ::: "memory");   // tiles 0,1 landed
    __builtin_amdgcn_sched_barrier(0);
    XPAIR(0, 1, 0, 1)
    asm volatile("s_waitcnt lgkmcnt(0)" ::: "memory");
    __syncthreads();   // (B)

    int stg = 0;   // xbuf slot staged this round ( = t % 5 )
    int rs  = 2;   // xbuf slot holding tile t+2 at even-round top
    int gw  = 2;   // gbuf slot for g[t+2]
    for (int t = 0; t < T_STEPS; t += 2) {
      // even round: stage + produce pair (t+2, t+3)
      __builtin_amdgcn_s_barrier();
      asm volatile("" ::: "memory");
      STAGE(t + 5, stg)
      stg = (stg == 4) ? 0 : stg + 1;
      asm volatile("s_waitcnt vmcnt(8)" ::: "memory");  // tiles t+2,t+3 landed
      __builtin_amdgcn_sched_barrier(0);
      {
        const int rs1 = (rs == 4) ? 0 : rs + 1;
        XPAIR(rs, rs1, gw, (gw + 1) & 3)
        rs = (rs1 == 4) ? 0 : rs1 + 1;
        gw = (gw + 2) & 3;
      }
      asm volatile("s_waitcnt lgkmcnt(0)" ::: "memory");

      // odd round: stage only
      __builtin_amdgcn_s_barrier();
      asm volatile("" ::: "memory");
      STAGE(t + 6, stg)
      stg = (stg == 4) ? 0 : stg + 1;
    }
#undef XPAIR
#undef STAGE
  }
}

// ========== Kernel B: out-proj + softmax, fully parallel over T x B ==========
#define BBLOCKS 2048
__global__ __launch_bounds__(256) void lstm_out(
    const float* __restrict__ Wout, const float* __restrict__ bout_,
    float* __restrict__ out)
{
  const int tid  = threadIdx.x;
  const int wv   = tid >> 6;
  const int ln   = tid & 63;
  const int lrow = ln & 15;
  const int lkg  = ln >> 4;

  bf16x8 fragWo[8][2];
#pragma unroll
  for (int rf = 0; rf < 8; ++rf)
#pragma unroll
    for (int kf = 0; kf < 2; ++kf) {
      const float* p = Wout + (16 * rf + lrow) * HSZ + kf * 32 + 8 * lkg;
      bf16x8 f;
#pragma unroll
      for (int e = 0; e < 8; ++e) f[e] = (short)f2bf(p[e]);
      fragWo[rf][kf] = f;
    }
  f32x4 boV[8];
#pragma unroll
  for (int rf = 0; rf < 8; ++rf) boV[rf] = *(const f32x4*)&bout_[16 * rf + 4 * lkg];

  const unsigned short* hin = (const unsigned short*)out;
  const int NT = T_STEPS * (BATCH / 16);
  const int nw = BBLOCKS * 4;

  for (int tile = blockIdx.x * 4 + wv; tile < NT; tile += nw) {
    const int t  = tile >> 7;
    const int b0 = (tile & 127) * 16;

    const unsigned short* hr = hin + ((size_t)t * BATCH + b0 + lrow) * (2 * VSZ);
    const bf16x8 hb0 = *(const bf16x8*)&hr[8 * lkg];
    const bf16x8 hb1 = *(const bf16x8*)&hr[32 + 8 * lkg];

    f32x4 lac[8];
#pragma unroll
    for (int rf = 0; rf < 8; ++rf) {
      lac[rf] = boV[rf];
      lac[rf] = __builtin_amdgcn_mfma_f32_16x16x32_bf16(fragWo[rf][0], hb0, lac[rf], 0, 0, 0);
      lac[rf] = __builtin_amdgcn_mfma_f32_16x16x32_bf16(fragWo[rf][1], hb1, lac[rf], 0, 0, 0);
    }

    float m = -1e30f;
#pragma unroll
    for (int rf = 0; rf < 8; ++rf)
#pragma unroll
      for (int e = 0; e < 4; ++e) m = fmaxf(m, lac[rf][e]);
    m = fmaxf(m, __shfl_xor(m, 16));
    m = fmaxf(m, __shfl_xor(m, 32));
    float s = 0.0f;
#pragma unroll
    for (int rf = 0; rf < 8; ++rf)
#pragma unroll
      for (int e = 0; e < 4; ++e) {
        float p = __expf(lac[rf][e] - m);
        lac[rf][e] = p;
        s += p;
      }
    s += __shfl_xor(s, 16);
    s += __shfl_xor(s, 32);
    const float inv = 1.0f / s;

    float* orow = &out[((size_t)t * BATCH + b0 + lrow) * VSZ];
#pragma unroll
    for (int rf = 0; rf < 8; ++rf) {
      f32x4 pv = lac[rf] * inv;
      *(f32x4*)&orow[16 * rf + 4 * lkg] = pv;
    }
  }
}

extern "C" void kernel_launch(void* const* d_in, const int* in_sizes, int n_in,
                              void* d_out, int out_size, void* d_ws, size_t ws_size,
                              hipStream_t stream) {
  const float* x    = (const float*)d_in[0];
  const float* h0   = (const float*)d_in[1];
  const float* c0   = (const float*)d_in[2];
  const float* Wf   = (const float*)d_in[3];
  const float* bf_  = (const float*)d_in[4];
  const float* Wif  = (const float*)d_in[5];
  const float* bif_ = (const float*)d_in[6];
  const float* Wic  = (const float*)d_in[7];
  const float* bic_ = (const float*)d_in[8];
  const float* Wo   = (const float*)d_in[9];
  const float* bo_  = (const float*)d_in[10];
  const float* Wout = (const float*)d_in[11];
  const float* bout = (const float*)d_in[12];
  float* out = (float*)d_out;

  hipLaunchKernelGGL(lstm_rec, dim3(BATCH / MBLK), dim3(ATHREADS), 0, stream,
                     x, h0, c0, Wf, bf_, Wif, bif_, Wic, bic_, Wo, bo_, out);
  hipLaunchKernelGGL(lstm_out, dim3(BBLOCKS), dim3(256), 0, stream,
                     Wout, bout, out);
}